// Round 2
// baseline (573.302 us; speedup 1.0000x reference)
//
#include <hip/hip_runtime.h>
#include <math.h>

// Problem constants
#define TTOK   16384      // B*S tokens
#define HDIM   4096
#define ENUM   64         // experts
#define KTOP   6
#define GNUM   8
#define TGK    3
#define BBATCH 4
#define SSEQ   4096
#define ALPHAC 0.001f

// GEMM tiling
#define KSPLIT 4
#define BM     64
#define BK     64
#define KH     (HDIM / KSPLIT)   // 1024 per k-slice
#define NIT    (KH / BK)         // 16 iters
#define XSTR   68                // LDS row stride: 272B -> 2-way banks (free), 16B aligned
#define WSTR   68

// ---------------------------------------------------------------------------
// Kernel 0: W[64][4096] -> Wt[4096][64] so GEMM staging has no scatter writes
// ---------------------------------------------------------------------------
__global__ __launch_bounds__(256)
void transpose_w(const float* __restrict__ W, float* __restrict__ Wt) {
    __shared__ float T[64 * 65];
    const int tid = threadIdx.x;
    const int k0  = blockIdx.x * 64;
#pragma unroll
    for (int r = 0; r < 4; ++r) {
        const int q = r * 256 + tid;          // 1024 float4 granules
        const int e = q >> 4, c4 = q & 15;
        float4 v = *(const float4*)(W + (size_t)e * HDIM + k0 + c4 * 4);
        float* d = T + e * 65 + c4 * 4;
        d[0] = v.x; d[1] = v.y; d[2] = v.z; d[3] = v.w;
    }
    __syncthreads();
#pragma unroll
    for (int r = 0; r < 4; ++r) {
        const int q  = r * 256 + tid;
        const int k  = q >> 4;
        const int e4 = (q & 15) * 4;
        float4 v;
        v.x = T[(e4 + 0) * 65 + k];
        v.y = T[(e4 + 1) * 65 + k];
        v.z = T[(e4 + 2) * 65 + k];
        v.w = T[(e4 + 3) * 65 + k];
        *(float4*)(Wt + (size_t)(k0 + k) * ENUM + e4) = v;
    }
}

// ---------------------------------------------------------------------------
// Kernel 1: gate GEMM. lp[half][T][64] = X[:, slice] @ Wt[slice, :]
// ---------------------------------------------------------------------------
__global__ __launch_bounds__(256, 4)
void gate_gemm(const float* __restrict__ X, const float* __restrict__ Wt,
               float* __restrict__ lp) {
    __shared__ __align__(16) float Xs[BM * XSTR];
    __shared__ __align__(16) float Ws[BK * WSTR];   // [k][expert]

    const int tid  = threadIdx.x;
    const int bid  = blockIdx.x;
    const int tile = bid & 255;     // token tile 0..255
    const int half = bid >> 8;      // k-slice 0..3
    const int tok0 = tile * BM;
    const int k0   = half * KH;

    const int tx = tid & 15;        // expert col group: experts 4*tx..+3
    const int ty = tid >> 4;        // token row group: tokens 4*ty..+3

    const int c4 = tid & 15;        // float4 column for staging
    const int rw = tid >> 4;        // base row for staging

    float acc[4][4];
#pragma unroll
    for (int r = 0; r < 4; ++r)
#pragma unroll
        for (int c = 0; c < 4; ++c) acc[r][c] = 0.f;

    float4 xst[4], wst[4];

    // prefetch iter 0
#pragma unroll
    for (int p = 0; p < 4; ++p) {
        const int row = p * 16 + rw;    // token row / k row, 0..63
        xst[p] = *(const float4*)(X + (size_t)(tok0 + row) * HDIM + k0 + c4 * 4);
        wst[p] = *(const float4*)(Wt + (size_t)(k0 + row) * ENUM + c4 * 4);
    }

    for (int it = 0; it < NIT; ++it) {
        __syncthreads();
#pragma unroll
        for (int p = 0; p < 4; ++p) {
            const int row = p * 16 + rw;
            *(float4*)(Xs + row * XSTR + c4 * 4) = xst[p];
            *(float4*)(Ws + row * WSTR + c4 * 4) = wst[p];
        }
        __syncthreads();

        if (it + 1 < NIT) {
            const int kk = k0 + (it + 1) * BK;
#pragma unroll
            for (int p = 0; p < 4; ++p) {
                const int row = p * 16 + rw;
                xst[p] = *(const float4*)(X + (size_t)(tok0 + row) * HDIM + kk + c4 * 4);
                wst[p] = *(const float4*)(Wt + (size_t)(kk + row) * ENUM + c4 * 4);
            }
        }

#pragma unroll
        for (int ks = 0; ks < BK; ks += 4) {
            float4 xv[4], wv[4];
#pragma unroll
            for (int r = 0; r < 4; ++r)
                xv[r] = *(const float4*)(Xs + (4 * ty + r) * XSTR + ks);
#pragma unroll
            for (int j = 0; j < 4; ++j)
                wv[j] = *(const float4*)(Ws + (ks + j) * WSTR + 4 * tx);
#pragma unroll
            for (int r = 0; r < 4; ++r) {
                const float* xf = (const float*)&xv[r];
#pragma unroll
                for (int j = 0; j < 4; ++j) {
                    const float* wf = (const float*)&wv[j];
#pragma unroll
                    for (int c = 0; c < 4; ++c)
                        acc[r][c] = fmaf(xf[j], wf[c], acc[r][c]);
                }
            }
        }
    }

#pragma unroll
    for (int r = 0; r < 4; ++r) {
        float4 v = make_float4(acc[r][0], acc[r][1], acc[r][2], acc[r][3]);
        *(float4*)(lp + (size_t)half * TTOK * ENUM
                      + (size_t)(tok0 + 4 * ty + r) * ENUM + 4 * tx) = v;
    }
}

// ---------------------------------------------------------------------------
// Kernel 2: thread-per-token router. 64 tokens/block, 256 blocks.
// ---------------------------------------------------------------------------
#define RTOK 64
__global__ __launch_bounds__(256)
void router_topk(const float* __restrict__ lp,
                 float* __restrict__ out_idx, float* __restrict__ out_w,
                 float* __restrict__ ssum_g, int* __restrict__ cnt_g) {
    __shared__ float Ls[RTOK * 67];     // logits, stride 67 -> 2-way banks
    __shared__ float s_m[RTOK], s_inv[RTOK];
    __shared__ float s_ssum[ENUM];
    __shared__ int   s_cnt[ENUM];

    const int tid = threadIdx.x;
    const int t0  = blockIdx.x * RTOK;
    if (tid < ENUM) { s_cnt[tid] = 0; s_ssum[tid] = 0.f; }

    // stage logits: sum the KSPLIT partials, coalesced float4 reads
#pragma unroll
    for (int r = 0; r < 4; ++r) {
        const int q  = r * 256 + tid;         // 1024 granules = 64 tok x 16
        const int t  = q >> 4, c4 = q & 15;
        const size_t base = (size_t)(t0 + t) * ENUM + c4 * 4;
        float4 v = *(const float4*)(lp + base);
#pragma unroll
        for (int h = 1; h < KSPLIT; ++h) {
            float4 u = *(const float4*)(lp + (size_t)h * TTOK * ENUM + base);
            v.x += u.x; v.y += u.y; v.z += u.z; v.w += u.w;
        }
        float* d = Ls + t * 67 + c4 * 4;
        d[0] = v.x; d[1] = v.y; d[2] = v.z; d[3] = v.w;
    }
    __syncthreads();

    if (tid < RTOK) {
        const float* row = Ls + tid * 67;

        // group maxes + global max
        float gm[GNUM];
#pragma unroll
        for (int g = 0; g < GNUM; ++g) {
            float mg = row[g * 8];
#pragma unroll
            for (int j = 1; j < 8; ++j) mg = fmaxf(mg, row[g * 8 + j]);
            gm[g] = mg;
        }
        float m = gm[0];
#pragma unroll
        for (int g = 1; g < GNUM; ++g) m = fmaxf(m, gm[g]);

        // top-TG groups (rank with lowest-index tie-break)
        int selmask = 0;
#pragma unroll
        for (int g = 0; g < GNUM; ++g) {
            int rank = 0;
#pragma unroll
            for (int g2 = 0; g2 < GNUM; ++g2)
                rank += (gm[g2] > gm[g]) || (gm[g2] == gm[g] && g2 < g);
            selmask |= (rank < TGK) << g;
        }

        // single pass: softmax denom + branchless sorted top-6 insertion
        float v0=-1.f,v1=-1.f,v2=-1.f,v3=-1.f,v4=-1.f,v5=-1.f;
        float i0=0.f,i1=0.f,i2=0.f,i3=0.f,i4=0.f,i5=0.f;
        float s = 0.f;
#pragma unroll
        for (int e = 0; e < ENUM; ++e) {
            const float ex = expf(row[e] - m);
            s += ex;
            const float cand = ((selmask >> (e >> 3)) & 1) ? ex : -1.0f;
            const float fe = (float)e;
            const bool b0 = cand > v0, b1 = cand > v1, b2 = cand > v2,
                       b3 = cand > v3, b4 = cand > v4, b5 = cand > v5;
            v5 = b4 ? v4 : (b5 ? cand : v5);  i5 = b4 ? i4 : (b5 ? fe : i5);
            v4 = b3 ? v3 : (b4 ? cand : v4);  i4 = b3 ? i3 : (b4 ? fe : i4);
            v3 = b2 ? v2 : (b3 ? cand : v3);  i3 = b2 ? i2 : (b3 ? fe : i3);
            v2 = b1 ? v1 : (b2 ? cand : v2);  i2 = b1 ? i1 : (b2 ? fe : i2);
            v1 = b0 ? v0 : (b1 ? cand : v1);  i1 = b0 ? i0 : (b1 ? fe : i1);
            v0 = b0 ? cand : v0;              i0 = b0 ? fe : i0;
        }
        // weights: ex_j / sum(ex_top6) == score_j / sum(score_top6)
        const float invw = 1.0f / (v0 + v1 + v2 + v3 + v4 + v5);
        const int t = t0 + tid;
        float* oi = out_idx + (size_t)t * KTOP;
        float* ow = out_w   + (size_t)t * KTOP;
        oi[0]=i0; oi[1]=i1; oi[2]=i2; oi[3]=i3; oi[4]=i4; oi[5]=i5;
        ow[0]=v0*invw; ow[1]=v1*invw; ow[2]=v2*invw;
        ow[3]=v3*invw; ow[4]=v4*invw; ow[5]=v5*invw;

        atomicAdd(&s_cnt[(int)i0], 1); atomicAdd(&s_cnt[(int)i1], 1);
        atomicAdd(&s_cnt[(int)i2], 1); atomicAdd(&s_cnt[(int)i3], 1);
        atomicAdd(&s_cnt[(int)i4], 1); atomicAdd(&s_cnt[(int)i5], 1);
        s_m[tid] = m; s_inv[tid] = 1.0f / s;
    }
    __syncthreads();

    // per-expert score sums (transposed: lanes = experts, conflict-free)
    {
        const int e = tid & 63, strip = tid >> 6;
        float acc = 0.f;
#pragma unroll
        for (int i = 0; i < RTOK / 4; ++i) {
            const int t = strip * (RTOK / 4) + i;
            acc += expf(Ls[t * 67 + e] - s_m[t]) * s_inv[t];
        }
        atomicAdd(&s_ssum[e], acc);
    }
    __syncthreads();

    const int b = t0 / SSEQ;    // 64 tokens never straddle a batch
    if (tid < ENUM) {
        atomicAdd(&ssum_g[b * ENUM + tid], s_ssum[tid]);
        atomicAdd(&cnt_g[b * ENUM + tid], s_cnt[tid]);
    }
}

// ---------------------------------------------------------------------------
// Kernel 3: aux loss (1 block, 256 threads = 4 batches x 64 experts)
// ---------------------------------------------------------------------------
__global__ __launch_bounds__(256)
void aux_loss(const float* __restrict__ ssum_g, const int* __restrict__ cnt_g,
              float* __restrict__ out_aux) {
    const int tid = threadIdx.x;
    float v = (float)cnt_g[tid] * (float)ENUM / ((float)SSEQ * (float)KTOP)
            * (ssum_g[tid] / (float)SSEQ);
#pragma unroll
    for (int off = 32; off; off >>= 1) v += __shfl_xor(v, off);
    __shared__ float red[4];
    if ((tid & 63) == 0) red[tid >> 6] = v;
    __syncthreads();
    if (tid == 0)
        out_aux[0] = (red[0] + red[1] + red[2] + red[3]) * (ALPHAC / (float)BBATCH);
}

// ---------------------------------------------------------------------------
extern "C" void kernel_launch(void* const* d_in, const int* in_sizes, int n_in,
                              void* d_out, int out_size, void* d_ws, size_t ws_size,
                              hipStream_t stream) {
    const float* X = (const float*)d_in[0];   // [4,4096,4096] fp32
    const float* W = (const float*)d_in[1];   // [64,4096] fp32

    float* out     = (float*)d_out;
    float* out_idx = out;                           // [T*6] indices (as float)
    float* out_w   = out + (size_t)TTOK * KTOP;     // [T*6] weights
    float* out_aux = out + (size_t)2 * TTOK * KTOP; // scalar

    float* lp     = (float*)d_ws;                        // [4][T][64] = 16 MiB
    float* Wt     = lp + (size_t)KSPLIT * TTOK * ENUM;   // [4096][64] = 1 MiB
    float* ssum_g = Wt + (size_t)HDIM * ENUM;            // [4][64]
    int*   cnt_g  = (int*)(ssum_g + BBATCH * ENUM);      // [4][64]

    hipMemsetAsync(ssum_g, 0, BBATCH * ENUM * (sizeof(float) + sizeof(int)), stream);

    transpose_w<<<HDIM / 64, 256, 0, stream>>>(W, Wt);
    gate_gemm<<<256 * KSPLIT, 256, 0, stream>>>(X, Wt, lp);
    router_topk<<<TTOK / RTOK, 256, 0, stream>>>(lp, out_idx, out_w, ssum_g, cnt_g);
    aux_loss<<<1, 256, 0, stream>>>(ssum_g, cnt_g, out_aux);
}

// Round 3
// 497.825 us; speedup vs baseline: 1.1516x; 1.1516x over previous
//
#include <hip/hip_runtime.h>
#include <math.h>

// Problem constants
#define TTOK   16384
#define HDIM   4096
#define ENUM   64
#define KTOP   6
#define GNUM   8
#define TGK    3
#define BBATCH 4
#define SSEQ   4096
#define ALPHAC 0.001f

// GEMM tiling
#define KSPLIT 4
#define KSL    (HDIM / KSPLIT)   // 1024 k per slice
#define BK     64
#define GNIT   (KSL / BK)        // 16 iterations

#define AS3(p) ((__attribute__((address_space(3))) void*)(p))
#define AS1(p) ((const __attribute__((address_space(1))) void*)(p))

// ---------------------------------------------------------------------------
// Kernel 0: pack W[64][4096] -> Wp[k4][e][4]  (k-chunks of 4, expert-major)
// so a wave's per-step W slice (8 experts x 4 k) is 128 B contiguous.
// ---------------------------------------------------------------------------
__global__ __launch_bounds__(256)
void pack_w(const float* __restrict__ W, float* __restrict__ Wp) {
    const int gid = blockIdx.x * 256 + threadIdx.x;   // 0..65535
    const int k4 = gid >> 6, e = gid & 63;
    float4 v = *(const float4*)(W + (size_t)e * HDIM + k4 * 4);
    *(float4*)(Wp + (size_t)gid * 4) = v;
}

// ---------------------------------------------------------------------------
// Kernel 1: gate GEMM. Block = 64 tokens x 64 experts, 8 waves.
// lane = token; wave w = experts 8w..8w+7. X via global_load_lds (swizzled),
// W via wave-uniform (scalar) loads. lp[slice][t][e] partials.
// ---------------------------------------------------------------------------
__global__ __launch_bounds__(512, 4)
void gate_gemm(const float* __restrict__ X, const float* __restrict__ Wp,
               float* __restrict__ lp) {
    __shared__ __align__(16) float Xs[2][64 * 64];   // 2 x 16 KB

    const int tid = threadIdx.x;
    const int w   = __builtin_amdgcn_readfirstlane(tid >> 6);  // wave 0..7
    const int l   = tid & 63;                                  // lane = token
    const int tile  = blockIdx.x & 255;
    const int slice = blockIdx.x >> 8;
    const int tok0  = tile * 64;
    const int k0    = slice * KSL;

    // staging: wave w covers tokens 8w..8w+7 (2 calls x 4 tokens x 16 lanes)
    const int t0 = w * 8 + (l >> 4);          // call 0 token
    const int t1 = t0 + 4;                    // call 1 token
    const int q0 = (l & 15) ^ (t0 & 15);      // swizzled float4 slot
    const int q1 = (l & 15) ^ (t1 & 15);
    const float* g0 = X + (size_t)(tok0 + t0) * HDIM + k0 + q0 * 4;
    const float* g1 = X + (size_t)(tok0 + t1) * HDIM + k0 + q1 * 4;

    float acc[8];
#pragma unroll
    for (int j = 0; j < 8; ++j) acc[j] = 0.f;

    const float4* Wp4 = (const float4*)Wp;
    const int k4base  = k0 >> 2;              // slice*256
    const int w8      = w * 8;
    const int lm      = (l & 15);

    // prologue: stage iter 0 into buf 0
    __builtin_amdgcn_global_load_lds(AS1(g0), AS3(&Xs[0][w * 512 + 0]),   16, 0, 0);
    __builtin_amdgcn_global_load_lds(AS1(g1), AS3(&Xs[0][w * 512 + 256]), 16, 0, 0);

    for (int it = 0; it < GNIT; ++it) {
        __syncthreads();   // drains this iter's staging loads (vmcnt) + barrier
        if (it + 1 < GNIT) {
            const int buf = (it + 1) & 1;
            const size_t go = (size_t)(it + 1) * BK;
            __builtin_amdgcn_global_load_lds(AS1(g0 + go), AS3(&Xs[buf][w * 512 + 0]),   16, 0, 0);
            __builtin_amdgcn_global_load_lds(AS1(g1 + go), AS3(&Xs[buf][w * 512 + 256]), 16, 0, 0);
        }
        const float* xb = &Xs[it & 1][l * 64];
        const int k4it  = k4base + it * 16;
#pragma unroll
        for (int kq = 0; kq < 16; ++kq) {
            const float4 xv = *(const float4*)(xb + ((kq ^ lm) << 2));
            const size_t wb = (size_t)(k4it + kq) * 64 + w8;
#pragma unroll
            for (int j = 0; j < 8; ++j) {
                const float4 wv = Wp4[wb + j];   // wave-uniform -> s_load
                acc[j] = fmaf(xv.x, wv.x, acc[j]);
                acc[j] = fmaf(xv.y, wv.y, acc[j]);
                acc[j] = fmaf(xv.z, wv.z, acc[j]);
                acc[j] = fmaf(xv.w, wv.w, acc[j]);
            }
        }
    }

    float* dst = lp + (size_t)slice * TTOK * ENUM + (size_t)(tok0 + l) * ENUM + w8;
    *(float4*)(dst + 0) = make_float4(acc[0], acc[1], acc[2], acc[3]);
    *(float4*)(dst + 4) = make_float4(acc[4], acc[5], acc[6], acc[7]);
}

// ---------------------------------------------------------------------------
// Kernel 2: thread-per-token router. 64 tokens/block, 256 blocks.
// ---------------------------------------------------------------------------
#define RTOK 64
__global__ __launch_bounds__(256)
void router_topk(const float* __restrict__ lp,
                 float* __restrict__ out_idx, float* __restrict__ out_w,
                 float* __restrict__ ssum_g, int* __restrict__ cnt_g) {
    __shared__ float Ls[RTOK * 67];
    __shared__ float s_m[RTOK], s_inv[RTOK];
    __shared__ float s_ssum[ENUM];
    __shared__ int   s_cnt[ENUM];

    const int tid = threadIdx.x;
    const int t0  = blockIdx.x * RTOK;
    if (tid < ENUM) { s_cnt[tid] = 0; s_ssum[tid] = 0.f; }

#pragma unroll
    for (int r = 0; r < 4; ++r) {
        const int q  = r * 256 + tid;
        const int t  = q >> 4, c4 = q & 15;
        const size_t base = (size_t)(t0 + t) * ENUM + c4 * 4;
        float4 v = *(const float4*)(lp + base);
#pragma unroll
        for (int h = 1; h < KSPLIT; ++h) {
            float4 u = *(const float4*)(lp + (size_t)h * TTOK * ENUM + base);
            v.x += u.x; v.y += u.y; v.z += u.z; v.w += u.w;
        }
        float* d = Ls + t * 67 + c4 * 4;
        d[0] = v.x; d[1] = v.y; d[2] = v.z; d[3] = v.w;
    }
    __syncthreads();

    if (tid < RTOK) {
        const float* row = Ls + tid * 67;

        float gm[GNUM];
#pragma unroll
        for (int g = 0; g < GNUM; ++g) {
            float mg = row[g * 8];
#pragma unroll
            for (int j = 1; j < 8; ++j) mg = fmaxf(mg, row[g * 8 + j]);
            gm[g] = mg;
        }
        float m = gm[0];
#pragma unroll
        for (int g = 1; g < GNUM; ++g) m = fmaxf(m, gm[g]);

        int selmask = 0;
#pragma unroll
        for (int g = 0; g < GNUM; ++g) {
            int rank = 0;
#pragma unroll
            for (int g2 = 0; g2 < GNUM; ++g2)
                rank += (gm[g2] > gm[g]) || (gm[g2] == gm[g] && g2 < g);
            selmask |= (rank < TGK) << g;
        }

        float v0=-1.f,v1=-1.f,v2=-1.f,v3=-1.f,v4=-1.f,v5=-1.f;
        float i0=0.f,i1=0.f,i2=0.f,i3=0.f,i4=0.f,i5=0.f;
        float s = 0.f;
#pragma unroll
        for (int e = 0; e < ENUM; ++e) {
            const float ex = __expf(row[e] - m);
            s += ex;
            const float cand = ((selmask >> (e >> 3)) & 1) ? ex : -1.0f;
            const float fe = (float)e;
            const bool b0 = cand > v0, b1 = cand > v1, b2 = cand > v2,
                       b3 = cand > v3, b4 = cand > v4, b5 = cand > v5;
            v5 = b4 ? v4 : (b5 ? cand : v5);  i5 = b4 ? i4 : (b5 ? fe : i5);
            v4 = b3 ? v3 : (b4 ? cand : v4);  i4 = b3 ? i3 : (b4 ? fe : i4);
            v3 = b2 ? v2 : (b3 ? cand : v3);  i3 = b2 ? i2 : (b3 ? fe : i3);
            v2 = b1 ? v1 : (b2 ? cand : v2);  i2 = b1 ? i1 : (b2 ? fe : i2);
            v1 = b0 ? v0 : (b1 ? cand : v1);  i1 = b0 ? i0 : (b1 ? fe : i1);
            v0 = b0 ? cand : v0;              i0 = b0 ? fe : i0;
        }
        const float invw = 1.0f / (v0 + v1 + v2 + v3 + v4 + v5);
        const int t = t0 + tid;
        float* oi = out_idx + (size_t)t * KTOP;
        float* ow = out_w   + (size_t)t * KTOP;
        oi[0]=i0; oi[1]=i1; oi[2]=i2; oi[3]=i3; oi[4]=i4; oi[5]=i5;
        ow[0]=v0*invw; ow[1]=v1*invw; ow[2]=v2*invw;
        ow[3]=v3*invw; ow[4]=v4*invw; ow[5]=v5*invw;

        atomicAdd(&s_cnt[(int)i0], 1); atomicAdd(&s_cnt[(int)i1], 1);
        atomicAdd(&s_cnt[(int)i2], 1); atomicAdd(&s_cnt[(int)i3], 1);
        atomicAdd(&s_cnt[(int)i4], 1); atomicAdd(&s_cnt[(int)i5], 1);
        s_m[tid] = m; s_inv[tid] = 1.0f / s;
    }
    __syncthreads();

    {
        const int e = tid & 63, strip = tid >> 6;
        float acc = 0.f;
#pragma unroll
        for (int i = 0; i < RTOK / 4; ++i) {
            const int t = strip * (RTOK / 4) + i;
            acc += __expf(Ls[t * 67 + e] - s_m[t]) * s_inv[t];
        }
        atomicAdd(&s_ssum[e], acc);
    }
    __syncthreads();

    const int b = t0 / SSEQ;
    if (tid < ENUM) {
        atomicAdd(&ssum_g[b * ENUM + tid], s_ssum[tid]);
        atomicAdd(&cnt_g[b * ENUM + tid], s_cnt[tid]);
    }
}

// ---------------------------------------------------------------------------
// Kernel 3: aux loss (1 block)
// ---------------------------------------------------------------------------
__global__ __launch_bounds__(256)
void aux_loss(const float* __restrict__ ssum_g, const int* __restrict__ cnt_g,
              float* __restrict__ out_aux) {
    const int tid = threadIdx.x;
    float v = (float)cnt_g[tid] * (float)ENUM / ((float)SSEQ * (float)KTOP)
            * (ssum_g[tid] / (float)SSEQ);
#pragma unroll
    for (int off = 32; off; off >>= 1) v += __shfl_xor(v, off);
    __shared__ float red[4];
    if ((tid & 63) == 0) red[tid >> 6] = v;
    __syncthreads();
    if (tid == 0)
        out_aux[0] = (red[0] + red[1] + red[2] + red[3]) * (ALPHAC / (float)BBATCH);
}

// ---------------------------------------------------------------------------
extern "C" void kernel_launch(void* const* d_in, const int* in_sizes, int n_in,
                              void* d_out, int out_size, void* d_ws, size_t ws_size,
                              hipStream_t stream) {
    const float* X = (const float*)d_in[0];   // [4,4096,4096] fp32
    const float* W = (const float*)d_in[1];   // [64,4096] fp32

    float* out     = (float*)d_out;
    float* out_idx = out;
    float* out_w   = out + (size_t)TTOK * KTOP;
    float* out_aux = out + (size_t)2 * TTOK * KTOP;

    float* lp     = (float*)d_ws;                        // [4][T][64] = 16 MiB
    float* Wp     = lp + (size_t)KSPLIT * TTOK * ENUM;   // [1024][64][4] = 1 MiB
    float* ssum_g = Wp + (size_t)HDIM * ENUM;            // [4][64]
    int*   cnt_g  = (int*)(ssum_g + BBATCH * ENUM);      // [4][64]

    hipMemsetAsync(ssum_g, 0, BBATCH * ENUM * (sizeof(float) + sizeof(int)), stream);

    pack_w<<<(HDIM / 4) * ENUM / 256, 256, 0, stream>>>(W, Wp);
    gate_gemm<<<256 * KSPLIT, 512, 0, stream>>>(X, Wp, lp);
    router_topk<<<TTOK / RTOK, 256, 0, stream>>>(lp, out_idx, out_w, ssum_g, cnt_g);
    aux_loss<<<1, 256, 0, stream>>>(ssum_g, cnt_g, out_aux);
}